// Round 1
// baseline (297.025 us; speedup 1.0000x reference)
//
#include <hip/hip_runtime.h>
#include <hip/hip_bf16.h>

#define B_ 2
#define N_ 2048
#define E_ 1024
#define H_ 16
#define D_ 64
#define BH_ (B_ * H_)

typedef __attribute__((ext_vector_type(4))) float f32x4;
typedef __attribute__((ext_vector_type(8))) short bf16x8;
typedef __attribute__((ext_vector_type(4))) short s16x4;

#define MFMA(a, b, c) __builtin_amdgcn_mfma_f32_16x16x32_bf16(a, b, c, 0, 0, 0)

static __device__ __forceinline__ unsigned short f2bf(float f) {
    unsigned int u = __builtin_bit_cast(unsigned int, f);
    u += 0x7fff + ((u >> 16) & 1);   // RNE; inputs are finite
    return (unsigned short)(u >> 16);
}
static __device__ __forceinline__ float bf2f(unsigned short s) {
    unsigned int u = ((unsigned int)s) << 16;
    return __builtin_bit_cast(float, u);
}
static __device__ __forceinline__ bf16x8 cvt8(const float* __restrict__ p) {
    f32x4 a = *(const f32x4*)p;
    f32x4 b = *(const f32x4*)(p + 4);
    bf16x8 r;
    r[0] = (short)f2bf(a.x); r[1] = (short)f2bf(a.y);
    r[2] = (short)f2bf(a.z); r[3] = (short)f2bf(a.w);
    r[4] = (short)f2bf(b.x); r[5] = (short)f2bf(b.y);
    r[6] = (short)f2bf(b.z); r[7] = (short)f2bf(b.w);
    return r;
}

// ---------------------------------------------------------------------------
// Projection: out = X_head @ W[h]^T  (per head), bf16 output.
// mode 0: out layout [bh][n][d]   (for qh, kh)
// mode 1: out layout [bh][d][n]   (V transposed, for PV A-operand)
// grid (N/64, BH), block 256 (4 waves; wave = one 16-token m/n tile)
// ---------------------------------------------------------------------------
__global__ __launch_bounds__(256)
void proj_kernel(const float* __restrict__ X, const float* __restrict__ W,
                 unsigned short* __restrict__ out, int mode) {
    const int lane = threadIdx.x & 63;
    const int wave = threadIdx.x >> 6;
    const int l16  = lane & 15;
    const int quad = lane >> 4;
    const int bh = blockIdx.y;
    const int b = bh >> 4, h = bh & 15;
    const int n0 = blockIdx.x * 64;

    const int tok = n0 + wave * 16 + l16;
    const float* xrow = X + ((size_t)(b * N_ + tok)) * E_ + h * 64;
    bf16x8 xf[2];
    xf[0] = cvt8(xrow + quad * 8);
    xf[1] = cvt8(xrow + 32 + quad * 8);

    const float* Wh = W + (size_t)h * 64 * 64;
    bf16x8 wf[4][2];
#pragma unroll
    for (int t4 = 0; t4 < 4; ++t4) {
        const float* wrow = Wh + (t4 * 16 + l16) * 64;
        wf[t4][0] = cvt8(wrow + quad * 8);
        wf[t4][1] = cvt8(wrow + 32 + quad * 8);
    }

    if (mode == 0) {
#pragma unroll
        for (int t4 = 0; t4 < 4; ++t4) {
            f32x4 a = {0.f, 0.f, 0.f, 0.f};
            a = MFMA(xf[0], wf[t4][0], a);
            a = MFMA(xf[1], wf[t4][1], a);
#pragma unroll
            for (int r = 0; r < 4; ++r) {
                int tk = n0 + wave * 16 + quad * 4 + r;
                out[((size_t)bh * N_ + tk) * 64 + t4 * 16 + l16] = (unsigned short)f2bf(a[r]);
            }
        }
    } else {
#pragma unroll
        for (int mi = 0; mi < 4; ++mi) {
            f32x4 a = {0.f, 0.f, 0.f, 0.f};
            a = MFMA(wf[mi][0], xf[0], a);
            a = MFMA(wf[mi][1], xf[1], a);
#pragma unroll
            for (int r = 0; r < 4; ++r) {
                int dout = mi * 16 + quad * 4 + r;
                out[((size_t)bh * 64 + dout) * N_ + (n0 + wave * 16 + l16)] =
                    (unsigned short)f2bf(a[r]);
            }
        }
    }
}

// ---------------------------------------------------------------------------
// Wo fp32 -> bf16 (layout unchanged: [e'][e])
// ---------------------------------------------------------------------------
__global__ __launch_bounds__(256)
void cvt_wo_kernel(const float* __restrict__ wo, unsigned short* __restrict__ wob) {
    int idx = blockIdx.x * 256 + threadIdx.x;
    f32x4 v = *(const f32x4*)(wo + (size_t)idx * 4);
    s16x4 r = {(short)f2bf(v.x), (short)f2bf(v.y), (short)f2bf(v.z), (short)f2bf(v.w)};
    *(s16x4*)(wob + (size_t)idx * 4) = r;
}

// ---------------------------------------------------------------------------
// Flash attention. grid (N/128, BH), block 256 = 4 waves.
// Wave handles 32 q rows (2 n-tiles). S^T = K*Q^T, O^T = V^T * P^T.
// qh/kh: [bh][n][d] bf16; vt: [bh][d][n] bf16; attn out: [b][n][e] bf16.
// ---------------------------------------------------------------------------
__global__ __launch_bounds__(256)
void attn_kernel(const unsigned short* __restrict__ qh,
                 const unsigned short* __restrict__ kh,
                 const unsigned short* __restrict__ vt,
                 const int* __restrict__ mask,
                 unsigned short* __restrict__ attnb) {
    __shared__ short Plds[4][32][72];   // per-wave P tile, padded stride

    const int lane = threadIdx.x & 63;
    const int wave = threadIdx.x >> 6;
    const int l16  = lane & 15;
    const int quad = lane >> 4;
    const int bh = blockIdx.y;
    const int b = bh >> 4, h = bh & 15;
    const int q0 = blockIdx.x * 128 + wave * 32;

    // Q fragments: scale by 1/32 (exact in bf16), zero masked query rows
    bf16x8 qf[2][2];
#pragma unroll
    for (int qi = 0; qi < 2; ++qi) {
        int q = q0 + qi * 16 + l16;
        int mk = mask[b * N_ + q];
        const unsigned short* qrow = qh + ((size_t)bh * N_ + q) * 64;
#pragma unroll
        for (int c = 0; c < 2; ++c) {
            bf16x8 raw = *(const bf16x8*)(qrow + c * 32 + quad * 8);
            bf16x8 t;
#pragma unroll
            for (int j = 0; j < 8; ++j) {
                float f = bf2f((unsigned short)raw[j]) * 0.03125f;
                t[j] = mk ? (short)f2bf(f) : (short)0;
            }
            qf[qi][c] = t;
        }
    }

    float mI[2] = {-1e30f, -1e30f};
    float lI[2] = {0.f, 0.f};
    f32x4 o[4][2];
#pragma unroll
    for (int mi = 0; mi < 4; ++mi)
#pragma unroll
        for (int qi = 0; qi < 2; ++qi) o[mi][qi] = (f32x4){0.f, 0.f, 0.f, 0.f};

    for (int kt = 0; kt < N_ / 64; ++kt) {
        const int k0 = kt * 64;

        bf16x8 ka[4][2];
#pragma unroll
        for (int t4 = 0; t4 < 4; ++t4) {
            const unsigned short* krow = kh + ((size_t)bh * N_ + k0 + t4 * 16 + l16) * 64;
            ka[t4][0] = *(const bf16x8*)(krow + quad * 8);
            ka[t4][1] = *(const bf16x8*)(krow + 32 + quad * 8);
        }

        f32x4 s[2][4];
#pragma unroll
        for (int qi = 0; qi < 2; ++qi)
#pragma unroll
            for (int t4 = 0; t4 < 4; ++t4) {
                f32x4 z = {0.f, 0.f, 0.f, 0.f};
                z = MFMA(ka[t4][0], qf[qi][0], z);
                z = MFMA(ka[t4][1], qf[qi][1], z);
                s[qi][t4] = z;
            }

#pragma unroll
        for (int qi = 0; qi < 2; ++qi) {
            float tm = fmaxf(fmaxf(s[qi][0].x, s[qi][0].y), fmaxf(s[qi][0].z, s[qi][0].w));
#pragma unroll
            for (int t4 = 1; t4 < 4; ++t4) {
                float t = fmaxf(fmaxf(s[qi][t4].x, s[qi][t4].y),
                                fmaxf(s[qi][t4].z, s[qi][t4].w));
                tm = fmaxf(tm, t);
            }
            tm = fmaxf(tm, __shfl_xor(tm, 16));
            tm = fmaxf(tm, __shfl_xor(tm, 32));
            float mnew = fmaxf(mI[qi], tm);
            float alpha = __builtin_amdgcn_exp2f((mI[qi] - mnew) * 1.44269504f);
            mI[qi] = mnew;
            float rsum = 0.f;
#pragma unroll
            for (int t4 = 0; t4 < 4; ++t4) {
#pragma unroll
                for (int r = 0; r < 4; ++r) {
                    float p = __builtin_amdgcn_exp2f((s[qi][t4][r] - mnew) * 1.44269504f);
                    s[qi][t4][r] = p;
                    rsum += p;
                }
            }
            rsum += __shfl_xor(rsum, 16);
            rsum += __shfl_xor(rsum, 32);
            lI[qi] = lI[qi] * alpha + rsum;
#pragma unroll
            for (int mi = 0; mi < 4; ++mi) {
                o[mi][qi].x *= alpha; o[mi][qi].y *= alpha;
                o[mi][qi].z *= alpha; o[mi][qi].w *= alpha;
            }
            // pack P (4 consecutive keys per reg group) into LDS
#pragma unroll
            for (int t4 = 0; t4 < 4; ++t4) {
                s16x4 pk = {(short)f2bf(s[qi][t4].x), (short)f2bf(s[qi][t4].y),
                            (short)f2bf(s[qi][t4].z), (short)f2bf(s[qi][t4].w)};
                *(s16x4*)(&Plds[wave][qi * 16 + l16][t4 * 16 + quad * 4]) = pk;
            }
        }
        asm volatile("s_waitcnt lgkmcnt(0)" ::: "memory");

        bf16x8 pb[2][2];
#pragma unroll
        for (int qi = 0; qi < 2; ++qi) {
            pb[qi][0] = *(const bf16x8*)(&Plds[wave][qi * 16 + l16][quad * 8]);
            pb[qi][1] = *(const bf16x8*)(&Plds[wave][qi * 16 + l16][32 + quad * 8]);
        }
#pragma unroll
        for (int mi = 0; mi < 4; ++mi) {
            const unsigned short* vrow = vt + ((size_t)bh * 64 + mi * 16 + l16) * N_ + k0;
            bf16x8 va0 = *(const bf16x8*)(vrow + quad * 8);
            bf16x8 va1 = *(const bf16x8*)(vrow + 32 + quad * 8);
#pragma unroll
            for (int qi = 0; qi < 2; ++qi) {
                o[mi][qi] = MFMA(va0, pb[qi][0], o[mi][qi]);
                o[mi][qi] = MFMA(va1, pb[qi][1], o[mi][qi]);
            }
        }
    }

#pragma unroll
    for (int qi = 0; qi < 2; ++qi) {
        float inv = 1.0f / lI[qi];
        int q = q0 + qi * 16 + l16;
#pragma unroll
        for (int mi = 0; mi < 4; ++mi) {
            f32x4 ov = o[mi][qi];
            s16x4 pk = {(short)f2bf(ov.x * inv), (short)f2bf(ov.y * inv),
                        (short)f2bf(ov.z * inv), (short)f2bf(ov.w * inv)};
            int d0 = mi * 16 + quad * 4;
            *(s16x4*)(attnb + ((size_t)(b * N_ + q)) * E_ + h * 64 + d0) = pk;
        }
    }
}

// ---------------------------------------------------------------------------
// out = attn(bf16) @ Wo^T(bf16), fp32 out. grid (B*N/128, E/64), block 256.
// Wave: 32 token rows (2 m-tiles) x 64 out-cols (4 n-tiles).
// ---------------------------------------------------------------------------
__global__ __launch_bounds__(256)
void out_gemm_kernel(const unsigned short* __restrict__ attnb,
                     const unsigned short* __restrict__ wob,
                     float* __restrict__ out) {
    const int lane = threadIdx.x & 63;
    const int wave = threadIdx.x >> 6;
    const int l16  = lane & 15;
    const int quad = lane >> 4;
    const int t0 = blockIdx.x * 128 + wave * 32;
    const int c0 = blockIdx.y * 64;

    f32x4 acc[2][4];
#pragma unroll
    for (int mi = 0; mi < 2; ++mi)
#pragma unroll
        for (int t4 = 0; t4 < 4; ++t4) acc[mi][t4] = (f32x4){0.f, 0.f, 0.f, 0.f};

    for (int kc = 0; kc < E_ / 32; ++kc) {
        bf16x8 a[2], bb[4];
#pragma unroll
        for (int mi = 0; mi < 2; ++mi)
            a[mi] = *(const bf16x8*)(attnb + (size_t)(t0 + mi * 16 + l16) * E_ +
                                     kc * 32 + quad * 8);
#pragma unroll
        for (int t4 = 0; t4 < 4; ++t4)
            bb[t4] = *(const bf16x8*)(wob + (size_t)(c0 + t4 * 16 + l16) * E_ +
                                      kc * 32 + quad * 8);
#pragma unroll
        for (int mi = 0; mi < 2; ++mi)
#pragma unroll
            for (int t4 = 0; t4 < 4; ++t4)
                acc[mi][t4] = MFMA(a[mi], bb[t4], acc[mi][t4]);
    }

#pragma unroll
    for (int mi = 0; mi < 2; ++mi)
#pragma unroll
        for (int t4 = 0; t4 < 4; ++t4)
#pragma unroll
            for (int r = 0; r < 4; ++r)
                out[(size_t)(t0 + mi * 16 + quad * 4 + r) * E_ + c0 + t4 * 16 + l16] =
                    acc[mi][t4][r];
}

// ---------------------------------------------------------------------------
extern "C" void kernel_launch(void* const* d_in, const int* in_sizes, int n_in,
                              void* d_out, int out_size, void* d_ws, size_t ws_size,
                              hipStream_t stream) {
    const float* q    = (const float*)d_in[0];
    const float* k    = (const float*)d_in[1];
    const float* v    = (const float*)d_in[2];
    const int*   mask = (const int*)d_in[3];
    const float* Wq   = (const float*)d_in[4];
    const float* Wk   = (const float*)d_in[5];
    const float* Wv   = (const float*)d_in[6];
    const float* Wo   = (const float*)d_in[7];
    float* out = (float*)d_out;

    char* ws = (char*)d_ws;
    unsigned short* qh    = (unsigned short*)(ws);
    unsigned short* kh    = (unsigned short*)(ws + (size_t)8 * 1024 * 1024);
    unsigned short* vt    = (unsigned short*)(ws + (size_t)16 * 1024 * 1024);
    unsigned short* attnb = (unsigned short*)(ws + (size_t)24 * 1024 * 1024);
    // wob aliases qh's region: cvt_wo runs AFTER the attention kernel is done
    // reading qh, and only the final GEMM reads wob.
    unsigned short* wob   = (unsigned short*)(ws);

    dim3 blk(256);
    proj_kernel<<<dim3(N_ / 64, BH_), blk, 0, stream>>>(q, Wq, qh, 0);
    proj_kernel<<<dim3(N_ / 64, BH_), blk, 0, stream>>>(k, Wk, kh, 0);
    proj_kernel<<<dim3(N_ / 64, BH_), blk, 0, stream>>>(v, Wv, vt, 1);
    attn_kernel<<<dim3(N_ / 128, BH_), blk, 0, stream>>>(qh, kh, vt, mask, attnb);
    cvt_wo_kernel<<<dim3(E_ * E_ / 1024), blk, 0, stream>>>(Wo, wob);
    out_gemm_kernel<<<dim3(B_ * N_ / 128, E_ / 64), blk, 0, stream>>>(attnb, wob, out);
}